// Round 4
// baseline (4506.886 us; speedup 1.0000x reference)
//
#include <hip/hip_runtime.h>
#include <hip/hip_cooperative_groups.h>
#include <cstdint>
#include <cstddef>

namespace cg = cooperative_groups;

// CCDecoder: 16-step input-feeding LSTM + Luong attention decoder.
// B=256, S=512, T=16, H=1024, E=512.
// R4: ONE persistent cooperative kernel (256 blocks x 1024 threads, 1/CU).
//     Phase 0: bf16 converts (gi-remapped W_ih/W_hh), bias, init, emb pre-GEMM.
//     Per step: gates GEMM+fused LSTM | W_in | online-softmax attn | W_out.
//     grid.sync() between phases (66 syncs replace ~73 launches).
//     GEMM: BM=64,BN=64,BK=64, 16 waves (one 16x16 frag each), 1 load/thread/
//     stage -> counted vmcnt(1) double-buffer, raw s_barrier, XOR-swizzled LDS.
//     h feedback ping-pongs (whbf0/whbf1) -- fixes R3's latent stage/epilogue race.

#define B_ 256
#define S_ 512
#define T_ 16
#define H_ 1024
#define E_ 512

typedef unsigned short u16;
using short8 = __attribute__((ext_vector_type(8))) short;
using f32x4  = __attribute__((ext_vector_type(4))) float;

__device__ __forceinline__ float bf2f(u16 u) {
  union { uint32_t i; float f; } v; v.i = ((uint32_t)u) << 16; return v.f;
}
__device__ __forceinline__ u16 f2bf(float f) {
  union { uint32_t i; float f; } v; v.f = f;
  uint32_t r = v.i + 0x7fffu + ((v.i >> 16) & 1u);
  return (u16)(r >> 16);
}
__device__ __forceinline__ float sigmoidf_(float x) { return 1.f / (1.f + __expf(-x)); }

__device__ __forceinline__ void gload_lds16(const void* g, void* l) {
  __builtin_amdgcn_global_load_lds(
      (const __attribute__((address_space(1))) void*)g,
      (__attribute__((address_space(3))) void*)l, 16, 0, 0);
}

struct Reg2 { const u16* A; int lda; const u16* B; int ldb; int kt; };

struct MegaP {
  const float* trg_emb; const float* h0; const float* c0; const float* ctx;
  const int* src_len;
  const float* W_ih; const float* W_hh; const float* b_ih; const float* b_hh;
  const float* W_in; const float* W_out;
  float* out;
  u16* wWih; u16* wWhh; u16* wWin; u16* wWout; u16* wemb;
  float* wbsum; float* wh32; float* wc; float* wGemb;
  u16* whbf0; u16* whbf1; u16* whtbf; u16* wtgt; u16* wwbf; u16* wctx;
  int ctx_bf;
};

union SMem {
  struct { u16 A[2][4096]; u16 B[2][4096]; } g;                    // 32 KB
  struct { float facc[8][1024]; float fm[16]; float fl[16]; } a;   // 32.1 KB
};

// One 64x64 output tile, 16 waves (4x4 wave grid, one 16x16 frag each).
// K composed of up to two regions (each kt 64-K tiles). Double-buffered:
// stage(t+1) issue -> vmcnt(1) -> barrier -> ds_read+MFMA (lgkm0+schedbar
// pinned) -> barrier. Loads: threads 0-511 A-chunk tid, 512-1023 B-chunk;
// exactly 1 per thread per stage (wave-uniform -> vmcnt count valid).
template <int EPI>  // 0: fp32->Cf(ldc 4096)  1: bf16->Cb  2: tanh->out+Cb  3: fused LSTM
__device__ void gemm_tile(SMem* sm, const int tid, const int m0, const int n0,
                          const Reg2 r0, const Reg2 r1,
                          float* __restrict__ Cf, u16* __restrict__ Cb,
                          const float* __restrict__ Ci,
                          const float* __restrict__ bsum,
                          float* __restrict__ cst, float* __restrict__ h32o,
                          u16* __restrict__ hbfo, const int tstep) {
  const int lane = tid & 63;
  const int wave = tid >> 6;
  const int nt = r0.kt + r1.kt;
  const int wm = ((wave >> 2) << 4);
  const int wn = ((wave & 3) << 4);
  const int row16 = lane & 15;
  const int kg = lane >> 4;

  auto stage = [&](int ti, int buf) {
    const bool fst = ti < r0.kt;
    const u16* Ap = fst ? r0.A : r1.A;
    const u16* Bp = fst ? r0.B : r1.B;
    const int lda = fst ? r0.lda : r1.lda;
    const int ldb = fst ? r0.ldb : r1.ldb;
    const int kr = (fst ? ti : ti - r0.kt) << 6;
    if (tid < 512) {
      const int row = tid >> 3, qs = tid & 7;
      gload_lds16(Ap + (size_t)(m0 + row) * lda + kr + ((qs ^ (row & 7)) << 3),
                  (char*)&sm->g.A[buf][0] + (wave << 10));
    } else {
      const int c = tid - 512;
      const int row = c >> 3, qs = c & 7;
      gload_lds16(Bp + (size_t)(n0 + row) * ldb + kr + ((qs ^ (row & 7)) << 3),
                  (char*)&sm->g.B[buf][0] + ((wave - 8) << 10));
    }
  };

  f32x4 acc = {0.f, 0.f, 0.f, 0.f};
  stage(0, 0);
  for (int ti = 0; ti < nt; ++ti) {
    const int buf = ti & 1;
    if (ti + 1 < nt) {
      stage(ti + 1, buf ^ 1);
      asm volatile("s_waitcnt vmcnt(1)" ::: "memory");
    } else {
      asm volatile("s_waitcnt vmcnt(0)" ::: "memory");
    }
    __builtin_amdgcn_s_barrier();
    const int Ra = wm + row16;
    const int Rb = wn + row16;
    short8 a0 = *(const short8*)((const char*)&sm->g.A[buf][0] + (size_t)((Ra << 3) + (kg ^ (Ra & 7))) * 16);
    short8 b0 = *(const short8*)((const char*)&sm->g.B[buf][0] + (size_t)((Rb << 3) + (kg ^ (Rb & 7))) * 16);
    short8 a1 = *(const short8*)((const char*)&sm->g.A[buf][0] + (size_t)((Ra << 3) + ((4 + kg) ^ (Ra & 7))) * 16);
    short8 b1 = *(const short8*)((const char*)&sm->g.B[buf][0] + (size_t)((Rb << 3) + ((4 + kg) ^ (Rb & 7))) * 16);
    asm volatile("s_waitcnt lgkmcnt(0)" ::: "memory");
    __builtin_amdgcn_sched_barrier(0);
    acc = __builtin_amdgcn_mfma_f32_16x16x32_bf16(a0, b0, acc, 0, 0, 0);
    acc = __builtin_amdgcn_mfma_f32_16x16x32_bf16(a1, b1, acc, 0, 0, 0);
    __builtin_amdgcn_sched_barrier(0);
    __builtin_amdgcn_s_barrier();
  }
  // C/D layout: col = lane&15, row = (lane>>4)*4 + r  [m89-verified]
#pragma unroll
  for (int r = 0; r < 4; ++r) {
    const int row = m0 + wm + (kg << 2) + r;
    const int col = n0 + wn + row16;
    float v = acc[r];
    if (EPI == 0) {
      Cf[(size_t)row * 4096 + col] = v;
    } else if (EPI == 1) {
      Cb[row * H_ + col] = f2bf(v);
    } else if (EPI == 2) {
      float tv = tanhf(v);
      Cf[(size_t)row * (T_ * H_) + tstep * H_ + col] = tv;
      Cb[row * H_ + col] = f2bf(tv);
    } else {
      // gate-interleaved: col&3 = gate(i,f,g,o), col>>2 = unit
      v += Ci[(size_t)row * (T_ * 4096) + col] + bsum[col];
      float v1 = __shfl_xor(v, 1);
      float v2 = __shfl_xor(v, 2);
      float v3 = __shfl_xor(v, 3);
      if ((lane & 3) == 0) {
        const int u = col >> 2;
        float iv = sigmoidf_(v);
        float fv = sigmoidf_(v1);
        float gv = tanhf(v2);
        float ov = sigmoidf_(v3);
        float cn = fv * cst[row * H_ + u] + iv * gv;
        float hn = ov * tanhf(cn);
        cst[row * H_ + u] = cn;
        h32o[row * H_ + u] = hn;
        hbfo[row * H_ + u] = f2bf(hn);
      }
    }
  }
}

// Online-softmax attention for batch row `bid`. 16 waves stride s; per wave
// running (m,l,acc[16]); hierarchical merge 16->8 (LDS 32KB) -> final.
__device__ void attn_phase(SMem* sm, const MegaP& P, const int bid, const int tid) {
  const int lane = tid & 63;
  const int wave = tid >> 6;
  const int len = P.src_len[bid];
  float tg[16];
  {
    const u16* tp = P.wtgt + bid * H_ + lane * 16;
    short8 v1 = *(const short8*)tp;
    short8 v2 = *(const short8*)(tp + 8);
#pragma unroll
    for (int j = 0; j < 8; ++j) { tg[j] = bf2f((u16)v1[j]); tg[8 + j] = bf2f((u16)v2[j]); }
  }
  float m = -1e30f, l = 0.f;
  float acc[16];
#pragma unroll
  for (int j = 0; j < 16; ++j) acc[j] = 0.f;

  if (P.ctx_bf) {
    const u16* cb = P.wctx + (size_t)bid * (S_ * H_);
    for (int s = wave; s < len; s += 16) {
      const u16* cr = cb + (size_t)s * H_ + lane * 16;
      short8 v1 = *(const short8*)cr;
      short8 v2 = *(const short8*)(cr + 8);
      float cf[16];
#pragma unroll
      for (int j = 0; j < 8; ++j) { cf[j] = bf2f((u16)v1[j]); cf[8 + j] = bf2f((u16)v2[j]); }
      float x = 0.f;
#pragma unroll
      for (int j = 0; j < 16; ++j) x += cf[j] * tg[j];
#pragma unroll
      for (int off = 1; off < 64; off <<= 1) x += __shfl_xor(x, off);
      if (x > m) {                      // wave-uniform after reduce
        float sc_ = __expf(m - x);
        l *= sc_;
#pragma unroll
        for (int j = 0; j < 16; ++j) acc[j] *= sc_;
        m = x;
      }
      float p = __expf(x - m);
      l += p;
#pragma unroll
      for (int j = 0; j < 16; ++j) acc[j] += p * cf[j];
    }
  } else {
    const float* cb = P.ctx + (size_t)bid * (S_ * H_);
    for (int s = wave; s < len; s += 16) {
      const float* cr = cb + (size_t)s * H_ + lane * 16;
      float cf[16];
#pragma unroll
      for (int j4 = 0; j4 < 4; ++j4) {
        float4 v = *(const float4*)(cr + j4 * 4);
        cf[j4 * 4] = v.x; cf[j4 * 4 + 1] = v.y; cf[j4 * 4 + 2] = v.z; cf[j4 * 4 + 3] = v.w;
      }
      float x = 0.f;
#pragma unroll
      for (int j = 0; j < 16; ++j) x += cf[j] * tg[j];
#pragma unroll
      for (int off = 1; off < 64; off <<= 1) x += __shfl_xor(x, off);
      if (x > m) {
        float sc_ = __expf(m - x);
        l *= sc_;
#pragma unroll
        for (int j = 0; j < 16; ++j) acc[j] *= sc_;
        m = x;
      }
      float p = __expf(x - m);
      l += p;
#pragma unroll
      for (int j = 0; j < 16; ++j) acc[j] += p * cf[j];
    }
  }

  if (wave >= 8) {
#pragma unroll
    for (int j4 = 0; j4 < 4; ++j4) {
      float4 v;
      v.x = acc[j4 * 4]; v.y = acc[j4 * 4 + 1]; v.z = acc[j4 * 4 + 2]; v.w = acc[j4 * 4 + 3];
      *(float4*)&sm->a.facc[wave - 8][lane * 16 + j4 * 4] = v;
    }
    if (lane == 0) { sm->a.fm[wave] = m; sm->a.fl[wave] = l; }
  }
  __syncthreads();
  if (wave < 8) {
    float pm = sm->a.fm[8 + wave];
    float pl = sm->a.fl[8 + wave];
    float M = fmaxf(m, pm);
    float e1 = __expf(m - M);
    float e2 = __expf(pm - M);
#pragma unroll
    for (int j4 = 0; j4 < 4; ++j4) {
      float4 pv = *(float4*)&sm->a.facc[wave][lane * 16 + j4 * 4];
      float4 nv;
      nv.x = acc[j4 * 4 + 0] * e1 + pv.x * e2;
      nv.y = acc[j4 * 4 + 1] * e1 + pv.y * e2;
      nv.z = acc[j4 * 4 + 2] * e1 + pv.z * e2;
      nv.w = acc[j4 * 4 + 3] * e1 + pv.w * e2;
      *(float4*)&sm->a.facc[wave][lane * 16 + j4 * 4] = nv;
    }
    if (lane == 0) { sm->a.fm[wave] = M; sm->a.fl[wave] = l * e1 + pl * e2; }
  }
  __syncthreads();
  float mstar = -1e30f;
#pragma unroll
  for (int w = 0; w < 8; ++w) mstar = fmaxf(mstar, sm->a.fm[w]);
  float lsum = 0.f, asum = 0.f;
#pragma unroll
  for (int w = 0; w < 8; ++w) {
    float e = __expf(sm->a.fm[w] - mstar);
    lsum += sm->a.fl[w] * e;
    asum += sm->a.facc[w][tid] * e;
  }
  P.wwbf[bid * H_ + tid] = f2bf(asum / lsum);
}

__global__ __launch_bounds__(1024, 4) void mega(MegaP P) {
  cg::grid_group grid = cg::this_grid();
  __shared__ SMem sm;
  const int tid = threadIdx.x;
  const int bid = blockIdx.x;
  const int gtid = bid * 1024 + tid;      // 262144 threads = B_*H_
  const int GSZ = 256 * 1024;

  // ---------------- phase 0a: converts / bias / init ----------------
  for (int i = gtid; i < 4096 * 384; i += GSZ) {        // W_ih 4096x1536 gi
    const int r = i / 384, c4 = i - r * 384;
    const int rp = ((r & 1023) << 2) + (r >> 10);
    float4 v = ((const float4*)P.W_ih)[i];
    ushort4 o; o.x = f2bf(v.x); o.y = f2bf(v.y); o.z = f2bf(v.z); o.w = f2bf(v.w);
    ((ushort4*)P.wWih)[(size_t)rp * 384 + c4] = o;
  }
  for (int i = gtid; i < 4096 * 256; i += GSZ) {        // W_hh 4096x1024 gi
    const int r = i >> 8, c4 = i & 255;
    const int rp = ((r & 1023) << 2) + (r >> 10);
    float4 v = ((const float4*)P.W_hh)[i];
    ushort4 o; o.x = f2bf(v.x); o.y = f2bf(v.y); o.z = f2bf(v.z); o.w = f2bf(v.w);
    ((ushort4*)P.wWhh)[(size_t)rp * 256 + c4] = o;
  }
  {                                                     // W_in 1024x1024
    float4 v = ((const float4*)P.W_in)[gtid];
    ushort4 o; o.x = f2bf(v.x); o.y = f2bf(v.y); o.z = f2bf(v.z); o.w = f2bf(v.w);
    ((ushort4*)P.wWin)[gtid] = o;
  }
  for (int i = gtid; i < 524288; i += GSZ) {            // W_out 1024x2048
    float4 v = ((const float4*)P.W_out)[i];
    ushort4 o; o.x = f2bf(v.x); o.y = f2bf(v.y); o.z = f2bf(v.z); o.w = f2bf(v.w);
    ((ushort4*)P.wWout)[i] = o;
  }
  for (int i = gtid; i < 524288; i += GSZ) {            // emb (B,T,E)
    float4 v = ((const float4*)P.trg_emb)[i];
    ushort4 o; o.x = f2bf(v.x); o.y = f2bf(v.y); o.z = f2bf(v.z); o.w = f2bf(v.w);
    ((ushort4*)P.wemb)[i] = o;
  }
  if (gtid < 4096) {                                    // bias (gi)
    const int cp = ((gtid & 1023) << 2) + (gtid >> 10);
    P.wbsum[cp] = P.b_ih[gtid] + P.b_hh[gtid];
  }
  {                                                     // init state
    float hv = P.h0[gtid];
    P.wh32[gtid] = hv;
    P.wc[gtid] = P.c0[gtid];
    u16 hb = f2bf(hv);
    P.whbf0[gtid] = hb;
    P.whtbf[gtid] = hb;
  }
  if (P.ctx_bf) {
    for (int i = gtid; i < 33554432; i += GSZ) {        // ctx (B,S,H)
      float4 v = ((const float4*)P.ctx)[i];
      ushort4 o; o.x = f2bf(v.x); o.y = f2bf(v.y); o.z = f2bf(v.z); o.w = f2bf(v.w);
      ((ushort4*)P.wctx)[i] = o;
    }
  }
  grid.sync();

  // ---------------- phase 0b: G_emb = emb @ W_ihE^T (4096x4096, K=512) ----
  {
    Reg2 ra = { P.wemb, E_, P.wWih, E_ + H_, 8 };
    Reg2 rb = { nullptr, 0, nullptr, 0, 0 };
    for (int tile = bid; tile < 4096; tile += 256) {
      const int m0 = (tile & 63) << 6;
      const int n0 = (tile >> 6) << 6;
      gemm_tile<0>(&sm, tid, m0, n0, ra, rb, P.wGemb, nullptr,
                   nullptr, nullptr, nullptr, nullptr, nullptr, 0);
    }
  }
  grid.sync();

  // ---------------- 16 decoder steps ----------------
  for (int t = 0; t < T_; ++t) {
    const u16* hcur = (t & 1) ? P.whbf1 : P.whbf0;
    u16* hnxt = (t & 1) ? P.whbf0 : P.whbf1;
    {  // A: gates + fused LSTM  (M=256, N=4096 gi, K=2048) -- 256 tiles
      const int m0 = (bid & 3) << 6;
      const int n0 = (bid >> 2) << 6;
      Reg2 ra = { P.whtbf, H_, P.wWih + E_, E_ + H_, 16 };
      Reg2 rb = { hcur,    H_, P.wWhh,      H_,      16 };
      gemm_tile<3>(&sm, tid, m0, n0, ra, rb, nullptr, nullptr,
                   P.wGemb + t * 4096, P.wbsum, P.wc, P.wh32, hnxt, 0);
    }
    grid.sync();
    if (bid < 64) {  // B: target = h @ W_in^T  (M=256, N=1024, K=1024)
      const int m0 = (bid & 3) << 6;
      const int n0 = (bid >> 2) << 6;
      Reg2 ra = { hnxt, H_, P.wWin, H_, 16 };
      Reg2 rb = { nullptr, 0, nullptr, 0, 0 };
      gemm_tile<1>(&sm, tid, m0, n0, ra, rb, nullptr, P.wtgt,
                   nullptr, nullptr, nullptr, nullptr, nullptr, 0);
    }
    grid.sync();
    attn_phase(&sm, P, bid, tid);   // C: attention (256 blocks = batch rows)
    grid.sync();
    if (bid < 64) {  // D: htilde = tanh([weighted,h] @ W_out^T) (K=2048)
      const int m0 = (bid & 3) << 6;
      const int n0 = (bid >> 2) << 6;
      Reg2 ra = { P.wwbf, H_, P.wWout,      2 * H_, 16 };
      Reg2 rb = { hnxt,   H_, P.wWout + H_, 2 * H_, 16 };
      gemm_tile<2>(&sm, tid, m0, n0, ra, rb, P.out, P.whtbf,
                   nullptr, nullptr, nullptr, nullptr, nullptr, t);
    }
    grid.sync();
  }

  // ---------------- final h, c -> out tail ----------------
  P.out[(size_t)B_ * T_ * H_ + gtid] = P.wh32[gtid];
  P.out[(size_t)B_ * T_ * H_ + B_ * H_ + gtid] = P.wc[gtid];
}

// ---------------------------------------------------------------- host
extern "C" void kernel_launch(void* const* d_in, const int* in_sizes, int n_in,
                              void* d_out, int out_size, void* d_ws, size_t ws_size,
                              hipStream_t stream) {
  char* w = (char*)d_ws;
  MegaP P;
  P.trg_emb = (const float*)d_in[0];
  P.h0      = (const float*)d_in[1];
  P.c0      = (const float*)d_in[2];
  P.ctx     = (const float*)d_in[3];
  P.src_len = (const int*)d_in[4];
  P.W_ih    = (const float*)d_in[5];
  P.W_hh    = (const float*)d_in[6];
  P.b_ih    = (const float*)d_in[7];
  P.b_hh    = (const float*)d_in[8];
  P.W_in    = (const float*)d_in[9];
  P.W_out   = (const float*)d_in[10];
  P.out     = (float*)d_out;

  size_t off = 0;
  auto alloc = [&](size_t bytes) { char* p = w + off; off += bytes; return p; };
  P.wWih  = (u16*)  alloc(12582912);   // 4096x1536 bf16 (gi rows)
  P.wWhh  = (u16*)  alloc(8388608);    // 4096x1024 bf16 (gi rows)
  P.wWin  = (u16*)  alloc(2097152);    // 1024x1024
  P.wWout = (u16*)  alloc(4194304);    // 1024x2048
  P.wemb  = (u16*)  alloc(4194304);    // 4096x512
  P.wbsum = (float*)alloc(16384);      // 4096 (gi)
  P.wh32  = (float*)alloc(1048576);    // 256x1024
  P.wc    = (float*)alloc(1048576);
  P.whbf0 = (u16*)  alloc(524288);
  P.whbf1 = (u16*)  alloc(524288);
  P.whtbf = (u16*)  alloc(524288);
  P.wtgt  = (u16*)  alloc(524288);
  P.wwbf  = (u16*)  alloc(524288);
  P.wGemb = (float*)alloc(67108864);   // 4096x4096 fp32
  size_t need_ctx = off + (size_t)268435456;
  P.wctx  = (u16*)  alloc(268435456);  // 256x512x1024 bf16
  P.ctx_bf = (ws_size >= need_ctx) ? 1 : 0;

  void* args[] = { (void*)&P };
  hipLaunchCooperativeKernel((const void*)mega, dim3(256), dim3(1024), args, 0, stream);
}